// Round 9
// baseline (152.327 us; speedup 1.0000x reference)
//
#include <hip/hip_runtime.h>

// DispNetC correlation volume: out[b,d,h,w] = mean_c L[b,c,h,w]*R[b,c,h,w-d]
// for w>=d, else 0.  f32 in / f32 out.
//
// R8 post-mortem: source-level load hoisting was DEFEATED by the scheduler
// (VGPR stayed 52 -> loads re-sunk into load->pack chains; <1 load/wave in
// flight; 1.5 TB/s latency-bound). R9: same kernel + sched_barrier(0) fence
// between the 64-load batch and the pack phase, forcing all loads to issue
// before any consumer schedules. Progressive vmcnt drain overlaps pack VALU.

typedef __attribute__((ext_vector_type(8))) short short8;   // MFMA A/B frag
typedef __attribute__((ext_vector_type(4))) float floatx4;  // MFMA C/D frag

#define NB 8
#define NC 256
#define NH 64
#define NWD 128
#define ND 40
#define KC 64                            // channels per team
#define TEAM_BYTES (2 * NWD * KC * 2)    // Ls+Rs (bf16) = 32 KB per team

__global__ __launch_bounds__(1024, 4) void corr_mfma6(
    const float* __restrict__ Lg,
    const float* __restrict__ Rg,
    float* __restrict__ out)
{
  __shared__ __align__(16) unsigned char smem[4 * TEAM_BYTES];  // 128 KB

  const int blk  = blockIdx.x;
  const int b    = blk >> 6;      // NH = 64
  const int h    = blk & 63;
  const int tid  = threadIdx.x;
  const int team = tid >> 8;      // 0..3: which 64-channel quarter
  const int ttid = tid & 255;
  const int lane = tid & 63;
  const int wavt = (tid >> 6) & 3;  // wave within team
  const int m    = lane & 15;
  const int q    = lane >> 4;

  unsigned short* Ls = (unsigned short*)(smem + team * TEAM_BYTES);
  unsigned short* Rs = Ls + NWD * KC;

  const int ws = ttid & 127;       // lane -> w (coalesced, 256B/wave-instr)
  const int ch = ttid >> 7;        // which 8-c slot within each 16-c group
  const size_t HW   = (size_t)NH * NWD;
  const size_t goff = (size_t)b * NC * HW + (size_t)h * NWD
                    + (size_t)(team * KC) * HW + ws;

  // ---- phase 1: issue ALL 64 loads; fence prevents the scheduler from
  //      sinking them back into load->pack latency chains ----
  float lf[32], rf[32];
  #pragma unroll
  for (int it = 0; it < 4; ++it) {
    const size_t g = goff + (size_t)(it * 16 + ch * 8) * HW;
    #pragma unroll
    for (int p = 0; p < 8; ++p) {
      lf[it * 8 + p] = Lg[g + (size_t)p * HW];
      rf[it * 8 + p] = Rg[g + (size_t)p * HW];
    }
  }
  __builtin_amdgcn_sched_barrier(0);  // nothing crosses: loads stay batched

  // ---- phase 2: round-half-up to bf16, pack pairs, write LDS ----
  // [w][c] layout, XOR-swizzled 8-c groups (verified 0-conflict in R6).
  #pragma unroll
  for (int it = 0; it < 4; ++it) {
    unsigned int lv[4], rv[4];
    #pragma unroll
    for (int p = 0; p < 4; ++p) {
      const unsigned int a0 = __float_as_uint(lf[it * 8 + 2 * p])     + 0x8000u;
      const unsigned int a1 = __float_as_uint(lf[it * 8 + 2 * p + 1]) + 0x8000u;
      lv[p] = (a0 >> 16) | (a1 & 0xFFFF0000u);
      const unsigned int b0 = __float_as_uint(rf[it * 8 + 2 * p])     + 0x8000u;
      const unsigned int b1 = __float_as_uint(rf[it * 8 + 2 * p + 1]) + 0x8000u;
      rv[p] = (b0 >> 16) | (b1 & 0xFFFF0000u);
    }
    const int grp = it * 2 + ch;                        // 8-c group, 0..7
    const int pos = ws * KC + ((grp ^ (ws & 7)) << 3);  // XOR swizzle
    *(uint4*)(&Ls[pos]) = make_uint4(lv[0], lv[1], lv[2], lv[3]);
    *(uint4*)(&Rs[pos]) = make_uint4(rv[0], rv[1], rv[2], rv[3]);
  }
  __syncthreads();

  // ---- band tiles (i, j=i+k), k=0..3; 26 tiles round-robined over 4 waves ----
  floatx4 acc[7];
  #pragma unroll
  for (int t = 0; t < 7; ++t) acc[t] = (floatx4){0.f, 0.f, 0.f, 0.f};
  #pragma unroll
  for (int ks = 0; ks < 2; ++ks) {       // two K=32 steps over the 64 channels
    #pragma unroll
    for (int tile = 0; tile < 26; ++tile) {
      if ((tile & 3) != wavt) continue;
      const int i  = (tile < 8) ? tile : (tile < 15) ? tile - 8
                   : (tile < 21) ? tile - 15 : tile - 21;
      const int k  = (tile < 8) ? 0 : (tile < 15) ? 1 : (tile < 21) ? 2 : 3;
      const int j  = i + k;
      const int tt = tile >> 2;
      const int ra = 16 * i + m;         // w' row for A (from R)
      const int rb = 16 * j + m;         // w  col for B (from L)
      const int grp = ks * 4 + q;        // lane reads c = 32*ks + 8*q + [0..7]
      const short8 av = *(const short8*)(&Rs[ra * KC + ((grp ^ (ra & 7)) << 3)]);
      const short8 bv = *(const short8*)(&Ls[rb * KC + ((grp ^ (rb & 7)) << 3)]);
      acc[tt] = __builtin_amdgcn_mfma_f32_16x16x32_bf16(av, bv, acc[tt], 0, 0, 0);
    }
  }
  __syncthreads();  // all teams done reading staged LDS

  // ---- dump partial tiles (f32) into own team's region ----
  float* P = (float*)(smem + team * TEAM_BYTES);
  #pragma unroll
  for (int tile = 0; tile < 26; ++tile) {
    if ((tile & 3) != wavt) continue;
    const int tt = tile >> 2;
    #pragma unroll
    for (int r = 0; r < 4; ++r)
      P[tile * 256 + (q * 4 + r) * 16 + m] = acc[tt][r];
  }
  __syncthreads();

  // ---- reduce the 4 team partials and store (also zero-fills w<d) ----
  for (int t = tid; t < ND * NWD; t += 1024) {
    const int d = t >> 7;
    const int w = t & 127;
    float v = 0.0f;
    if (w >= d) {
      const int wp  = w - d;
      const int i   = wp >> 4;
      const int k   = (w >> 4) - i;
      const int off = (k == 0) ? 0 : (k == 1) ? 8 : (k == 2) ? 15 : 21;
      const int idx = (off + i) * 256 + (wp & 15) * 16 + (w & 15);
      v = (((const float*)(smem + 0 * TEAM_BYTES))[idx] +
           ((const float*)(smem + 1 * TEAM_BYTES))[idx]) +
          (((const float*)(smem + 2 * TEAM_BYTES))[idx] +
           ((const float*)(smem + 3 * TEAM_BYTES))[idx]);
      v *= 0.00390625f;  // /256 (mean over C)
    }
    out[(((size_t)b * ND + d) * NH + h) * NWD + w] = v;
  }
}

extern "C" void kernel_launch(void* const* d_in, const int* in_sizes, int n_in,
                              void* d_out, int out_size, void* d_ws, size_t ws_size,
                              hipStream_t stream) {
  corr_mfma6<<<dim3(NB * NH), dim3(1024), 0, stream>>>(
      (const float*)d_in[0], (const float*)d_in[1], (float*)d_out);
}

// Round 10
// 150.639 us; speedup vs baseline: 1.0112x; 1.0112x over previous
//
#include <hip/hip_runtime.h>

// DispNetC correlation volume: out[b,d,h,w] = mean_c L[b,c,h,w]*R[b,c,h,w-d]
// for w>=d, else 0.  f32 in / f32 out.
//
// R7-R9 proved the compiler always re-sinks VGPR staging loads into
// load->pack latency chains (<1 load/wave in flight, 1.5 TB/s, all pipes
// idle). This version stages via global_load_lds DMA (no dest register ->
// nothing to chain), double-buffered, with partial vmcnt waits + raw
// s_barrier (never __syncthreads: its vmcnt(0) drain kills the overlap).
// Compute is R6's hardware-validated 26-tile band MFMA.

typedef __attribute__((ext_vector_type(8))) short short8;   // MFMA A/B frag
typedef __attribute__((ext_vector_type(4))) float floatx4;  // MFMA C/D frag

#define NB 8
#define NC 256
#define NH 64
#define NWD 128
#define ND 40
#define KC 32      // channels per chunk; 8 chunks
// s_waitcnt imm: vm[3:0] | exp[6:4]=7 | lgkm[11:8] | vm[5:4]@[15:14]
#define WCNT(vm, lgkm) (((vm) & 15) | (((vm) >> 4) << 14) | (7 << 4) | ((lgkm) << 8))

typedef const __attribute__((address_space(1))) unsigned int guint;
typedef __attribute__((address_space(3))) unsigned int luint;

// LDS map (bytes):
//   f32 dbuf: z*32768 + arr*16384 + c*512 + w*4        (z=0/1, arr: 0=L 1=R)
//   bf16 buf: 65536 + arr*8192 + g*2048 + w*16 + e*2   (g = c-group of 8)

__global__ __launch_bounds__(256, 2) void corr_dma(
    const float* __restrict__ Lg,
    const float* __restrict__ Rg,
    float* __restrict__ out)
{
  __shared__ __align__(16) unsigned char smem[81920];

  const int blk  = blockIdx.x;
  const int b    = blk >> 6;       // NH = 64
  const int h    = blk & 63;
  const int tid  = threadIdx.x;
  const int lane = tid & 63;
  const int wave = tid >> 6;
  const int m    = lane & 15;
  const int q    = lane >> 4;

  const size_t HW   = (size_t)NH * NWD;
  const size_t goff = (size_t)b * NC * HW + (size_t)h * NWD;

  // ---- DMA issue: 8 width-16 global_load_lds per wave per chunk ----
  const int gl_c = (lane >> 5);        // lane 0-31 -> row c0, 32-63 -> c0+1
  const int gl_w = (lane & 31) * 4;    // 4 floats (16 B) per lane
  #define ISSUE_CHUNK(k)                                                        \
    {                                                                           \
      unsigned char* lbase = smem + (((k) & 1) << 15);                          \
      _Pragma("unroll")                                                         \
      for (int u = 0; u < 8; ++u) {                                             \
        const int s   = wave * 8 + u;                                           \
        const int arr = s >> 4;                                                 \
        const int idx = s & 15;                                                 \
        const float* src = arr ? Rg : Lg;                                       \
        const float* gp = src + goff +                                          \
            (size_t)((k) * KC + idx * 2 + gl_c) * HW + gl_w;                    \
        unsigned int* lp = (unsigned int*)(lbase + arr * 16384 + idx * 1024);   \
        __builtin_amdgcn_global_load_lds((guint*)gp, (luint*)lp, 16, 0, 0);     \
      }                                                                         \
    }

  floatx4 acc[7];
  #pragma unroll
  for (int t = 0; t < 7; ++t) acc[t] = (floatx4){0.f, 0.f, 0.f, 0.f};

  // convert-phase thread mapping: 8c x 4w block per thread
  const int cv_a  = tid >> 7;          // 0 = L, 1 = R
  const int cv_cb = (tid >> 5) & 3;    // c-group (8 channels)
  const int cv_w0 = (tid & 31) << 2;   // 4 consecutive w

  ISSUE_CHUNK(0);

  for (int k = 0; k < NC / KC; ++k) {
    if (k + 1 < NC / KC) {
      ISSUE_CHUNK(k + 1);
      __builtin_amdgcn_s_waitcnt(WCNT(8, 0));  // chunk k drained; k+1 in flight
    } else {
      __builtin_amdgcn_s_waitcnt(WCNT(0, 0));
    }
    __builtin_amdgcn_s_barrier();

    // ---- convert: f32 [c][w] -> bf16 [g][w][8] (round-half-up) ----
    {
      const float* fbuf = (const float*)(smem + ((k & 1) << 15) + cv_a * 16384);
      unsigned short* bbuf = (unsigned short*)(smem + 65536 + cv_a * 8192);
      float4 v[8];
      #pragma unroll
      for (int i = 0; i < 8; ++i)
        v[i] = *(const float4*)(fbuf + (cv_cb * 8 + i) * NWD + cv_w0);
      #pragma unroll
      for (int j = 0; j < 4; ++j) {
        unsigned int x[4];
        #pragma unroll
        for (int u = 0; u < 4; ++u) {
          const float lo = (&v[2 * u].x)[j];
          const float hi = (&v[2 * u + 1].x)[j];
          const unsigned int alo = __float_as_uint(lo) + 0x8000u;
          const unsigned int ahi = __float_as_uint(hi) + 0x8000u;
          x[u] = (alo >> 16) | (ahi & 0xFFFF0000u);
        }
        *(uint4*)(bbuf + cv_cb * 1024 + (cv_w0 + j) * 8) =
            make_uint4(x[0], x[1], x[2], x[3]);
      }
    }
    __builtin_amdgcn_s_waitcnt(WCNT(63, 0));   // own ds ops done (not DMA)
    __builtin_amdgcn_s_barrier();

    // ---- band tiles: one K=32 MFMA step per chunk ----
    {
      const unsigned short* Lb = (const unsigned short*)(smem + 65536);
      const unsigned short* Rb = Lb + 4096;
      #pragma unroll
      for (int tile = 0; tile < 26; ++tile) {
        if ((tile & 3) != wave) continue;
        const int i  = (tile < 8) ? tile : (tile < 15) ? tile - 8
                     : (tile < 21) ? tile - 15 : tile - 21;
        const int kk = (tile < 8) ? 0 : (tile < 15) ? 1 : (tile < 21) ? 2 : 3;
        const int j  = i + kk;
        const int tt = tile >> 2;
        const short8 av = *(const short8*)(Rb + q * 1024 + (16 * i + m) * 8);
        const short8 bv = *(const short8*)(Lb + q * 1024 + (16 * j + m) * 8);
        acc[tt] = __builtin_amdgcn_mfma_f32_16x16x32_bf16(av, bv, acc[tt], 0, 0, 0);
      }
    }
    __builtin_amdgcn_s_waitcnt(WCNT(63, 0));   // frag reads done before next convert
  }

  // ---- epilogue: D layout col=lane&15 (w in tile j), row=q*4+r (w' in tile i) ----
  #pragma unroll
  for (int tile = 0; tile < 26; ++tile) {
    if ((tile & 3) != wave) continue;
    const int i  = (tile < 8) ? tile : (tile < 15) ? tile - 8
                 : (tile < 21) ? tile - 15 : tile - 21;
    const int kk = (tile < 8) ? 0 : (tile < 15) ? 1 : (tile < 21) ? 2 : 3;
    const int j  = i + kk;
    const int tt = tile >> 2;
    const int w  = 16 * j + m;
    #pragma unroll
    for (int r = 0; r < 4; ++r) {
      const int wp = 16 * i + q * 4 + r;
      const int d  = w - wp;
      if (d >= 0 && d < ND)
        out[(((size_t)b * ND + d) * NH + h) * NWD + w] = acc[tt][r] * 0.00390625f;
    }
  }

  // ---- zero-fill the w < d triangle (d_out poisoned before each launch) ----
  for (int t = tid; t < ND * ND; t += 256) {
    const int d = t / ND;
    const int w = t - d * ND;
    if (w < d)
      out[(((size_t)b * ND + d) * NH + h) * NWD + w] = 0.0f;
  }
}

extern "C" void kernel_launch(void* const* d_in, const int* in_sizes, int n_in,
                              void* d_out, int out_size, void* d_ws, size_t ws_size,
                              hipStream_t stream) {
  corr_dma<<<dim3(NB * NH), dim3(256), 0, stream>>>(
      (const float*)d_in[0], (const float*)d_in[1], (float*)d_out);
}